// Round 4
// baseline (1108.079 us; speedup 1.0000x reference)
//
#include <hip/hip_runtime.h>
#include <math.h>

__device__ const int d_PERM[9] = {0,2,6,3,7,1,5,8,4};
__device__ const int d_DEG[9]  = {0,1,1,1,2,2,2,2,2};

__device__ __forceinline__ float silu_f(float x){ return x / (1.0f + __expf(-x)); }

// flag: 0 = int32 words, 1 = u8 bytes, 2 = float32 words, 3 = int64 (low word)
__device__ __forceinline__ int mask_at(const void* mp, int flag, int e){
  if (flag==1) return ((const unsigned char*)mp)[e] != 0;
  if (flag==3) return ((const unsigned int*)mp)[2*e] != 0u;
  return ((const unsigned int*)mp)[e] != 0u;
}

// ---------------- mask dtype detect (reads only 4096-byte prefix, safe under all interps) ----
__global__ void k_detect(const unsigned int* __restrict__ w, int* __restrict__ flag){
  __shared__ int notI, notF, anyOdd, anyEven;
  if (threadIdx.x==0){ notI=0; notF=0; anyOdd=0; anyEven=0; }
  __syncthreads();
  int li=0, lf=0, lo=0, le=0;
  for (int i = threadIdx.x; i < 1024; i += 256){
    unsigned int v = w[i];
    if (v != 0u && v != 1u) li = 1;
    if (v != 0u && v != 0x3F800000u) lf = 1;
    if (v != 0u){ if (i & 1) lo = 1; else le = 1; }
  }
  if (li) atomicOr(&notI,1);
  if (lf) atomicOr(&notF,1);
  if (lo) atomicOr(&anyOdd,1);
  if (le) atomicOr(&anyEven,1);
  __syncthreads();
  if (threadIdx.x==0){
    int f;
    if (!notI) f = (anyOdd || !anyEven) ? 0 : 3;   // int32 vs int64
    else       f = (!notF) ? 2 : 1;                 // float32 vs u8
    *flag = f;
  }
}

// ---------------- mega kernel: one block per atom, everything in LDS ----------------
__global__ __launch_bounds__(256) void k_mega(
    const float* __restrict__ x,      const float* __restrict__ w_in,  const float* __restrict__ b_in,
    const float* __restrict__ attn,
    const float* __restrict__ fdw,    const float* __restrict__ fdb,
    const float* __restrict__ few,    const float* __restrict__ feb,
    const float* __restrict__ es,     const float* __restrict__ et,
    const int*   __restrict__ an,     const int*   __restrict__ esrc,
    const float* __restrict__ d0w,    const float* __restrict__ d0b,
    const float* __restrict__ m1dw,   const float* __restrict__ m1db,
    const float* __restrict__ m2dw,   const float* __restrict__ m2db,
    const float* __restrict__ m0w1,   const float* __restrict__ m0w2,
    const float* __restrict__ m1w1r,  const float* __restrict__ m1w2r,
    const float* __restrict__ m1w1i,  const float* __restrict__ m1w2i,
    const float* __restrict__ m2w1r,  const float* __restrict__ m2w2r,
    const float* __restrict__ m2w1i,  const float* __restrict__ m2w2i,
    const float* __restrict__ wig,    const float* __restrict__ tg,   const float* __restrict__ fg,
    const float* __restrict__ w_out,  const float* __restrict__ b_out,
    const void*  __restrict__ maskp,  const int* __restrict__ flagp,
    float* __restrict__ out)
{
  __shared__ float acc[1152];     // masked-summed result per atom (orig channel order)
  __shared__ float htgt[1152];    // h[n]
  __shared__ float hsrc[1152];    // h[src(e)]
  __shared__ float xs[1152];      // wigner-rotated src, PERM layout
  __shared__ float xtl[1152];     // wigner-rotated tgt, PERM layout
  __shared__ float gg[1280];      // gates [b0: g0 g1r g1i g2r g2i][b1: same]
  __shared__ float P[2304];       // stage-1 outputs (then gated in place)
  __shared__ float Yb[1152];      // stage-2 output, orig channel order
  __shared__ float Zb[2304];      // grid output halves [2][1152]
  __shared__ float wl[81];        // wigner matrix of current edge
  __shared__ float xv[16];        // xe layer-1
  __shared__ float xe16[16];      // xe final

  const int n   = blockIdx.x;
  const int tid = threadIdx.x;
  const int f   = *flagp;

  for (int i = tid; i < 1152; i += 256) acc[i] = 0.f;

  // ---- htgt = h[n] (once per block) ----
  for (int idx = tid; idx < 1152; idx += 256){
    int j = idx >> 7, c = idx & 127;
    int deg = d_DEG[j];
    const float* wp = w_in + (size_t)deg*32768 + c;       // (3,256,128)
    const float* xp = x + ((size_t)n*9 + j)*256;
    float s = (j==0) ? b_in[c] : 0.f;
    for (int cc = 0; cc < 256; cc++) s += xp[cc] * wp[cc*128];
    htgt[idx] = s;
  }

  for (int k = 0; k < 8; k++){
    int e = n*8 + k;
    if (mask_at(maskp, f, e)) continue;      // masked edge contributes 0 (uniform per block)
    int src = esrc[e];

    __syncthreads();   // previous iteration fully consumed LDS

    // ---- A1: wigner load, xe layer-1, hsrc ----
    for (int i = tid; i < 81; i += 256) wl[i] = wig[(size_t)e*81 + i];
    if (tid < 16){
      int j = tid;
      float s = fdb[j] + es[(size_t)an[src]*16 + j] + et[(size_t)an[n]*16 + j];
      for (int kk = 0; kk < 32; kk++) s += attn[(size_t)e*32 + kk] * fdw[kk*16 + j];
      xv[j] = silu_f(s);
    }
    for (int idx = tid; idx < 1152; idx += 256){
      int j = idx >> 7, c = idx & 127;
      int deg = d_DEG[j];
      const float* wp = w_in + (size_t)deg*32768 + c;
      const float* xp = x + ((size_t)src*9 + j)*256;
      float s = (j==0) ? b_in[c] : 0.f;
      for (int cc = 0; cc < 256; cc++) s += xp[cc] * wp[cc*128];
      hsrc[idx] = s;
    }
    __syncthreads();

    // ---- A2: xe layer-2; xs/xt = wigner-rotate(+PERM) ----
    if (tid < 16){
      int j = tid;
      float s = feb[j];
      for (int kk = 0; kk < 16; kk++) s += xv[kk] * few[kk*16 + j];
      xe16[j] = silu_f(s);
    }
    for (int idx = tid; idx < 1152; idx += 256){
      int p = idx >> 7, c = idx & 127;
      int ch = d_PERM[p];
      float s1 = 0.f, s2 = 0.f;
      for (int j = 0; j < 9; j++){
        float wv = wl[ch*9 + j];
        s1 += wv * hsrc[j*128 + c];
        s2 += wv * htgt[j*128 + c];
      }
      xs[idx]  = s1;
      xtl[idx] = s2;
    }
    __syncthreads();

    // ---- A3: gates gg[1280] ----
    for (int col = tid; col < 1280; col += 256){
      int b = col / 640, r = col % 640;
      const float* w; float bias; int ldw, c2;
      if (r < 128){       w = d0w  + (size_t)b*2048; c2 = r;     ldw = 128; bias = d0b[b*128 + c2]; }
      else if (r < 384){  w = m1dw + (size_t)b*4096; c2 = r-128; ldw = 256; bias = m1db[b*256 + c2]; }
      else {              w = m2dw + (size_t)b*4096; c2 = r-384; ldw = 256; bias = m2db[b*256 + c2]; }
      float s = bias;
      for (int kk = 0; kk < 16; kk++) s += xe16[kk] * w[kk*ldw + c2];
      gg[col] = silu_f(s);
    }
    __syncthreads();

    // ---- A4: stage-1 P (layout: P0S@0 P0T@128 P1SR@256 P1SI@512 P1TR@768 P1TI@1024
    //                              P2SR@1280 P2SI@1536 P2TR@1792 P2TI@2048) ----
    for (int o = tid; o < 2304; o += 256){
      float s = 0.f;
      if (o < 256){
        int path = o >> 7, h = o & 127;
        const float* A  = path ? xtl : xs;
        const float* Wm = m0w1 + (size_t)path*49152 + h;        // (2,384,128)
        for (int i = 0; i < 384; i++) s += A[i] * Wm[i*128];
      } else if (o < 1280){
        int q = (o-256) >> 8; int rem = (o-256) & 255; int t = rem >> 7, h = rem & 127;
        const float* A  = ((q>=2) ? xtl : xs) + 384 + t*256;
        const float* Wm = ((q&1) ? m1w1i : m1w1r) + (size_t)((q>=2)?1:0)*32768 + h;  // (2,256,128)
        for (int i = 0; i < 256; i++) s += A[i] * Wm[i*128];
      } else {
        int q = (o-1280) >> 8; int rem = (o-1280) & 255; int t = rem >> 7, h = rem & 127;
        const float* A  = ((q>=2) ? xtl : xs) + 896 + t*128;
        const float* Wm = ((q&1) ? m2w1i : m2w1r) + (size_t)((q>=2)?1:0)*16384 + h;  // (2,128,128)
        for (int i = 0; i < 128; i++) s += A[i] * Wm[i*128];
      }
      P[o] = s;
    }
    __syncthreads();

    // ---- A5: gate P in place ----
    for (int o = tid; o < 2304; o += 256){
      int h = o & 127, goff;
      if (o < 256) goff = (o >> 7) ? 640 : 0;
      else if (o < 1280){ const int g1[4] = {128,256,768,896};   goff = g1[(o-256) >> 8]; }
      else              { const int g2[4] = {384,512,1024,1152}; goff = g2[(o-1280) >> 8]; }
      P[o] *= gg[goff + h];
    }
    __syncthreads();

    // ---- A6: stage-2 -> Yb (orig channel order) ----
    for (int o = tid; o < 1152; o += 256){
      float s = 0.f; int ch, c;
      if (o < 384){
        int g = o >> 7; c = o & 127;
        const int cm[3] = {0,2,6}; ch = cm[g];
        const float* w0 = m0w2 + o;                  // (2,128,384)
        for (int kk = 0; kk < 128; kk++)
          s += P[kk]*w0[kk*384] + P[128+kk]*w0[49152 + kk*384];
      } else if (o < 896){
        int om = o - 384; int tp = om >> 8; int col = om & 255;
        int g = col >> 7; c = col & 127;
        ch = tp ? (g ? 5 : 1) : (g ? 7 : 3);
        float sgn = tp ? 1.f : -1.f;
        const float* wr = m1w2r + col;               // (2,128,256)
        const float* wi = m1w2i + col;
        const float* pr0 = P + 256  + tp*128;        // SR[t']
        const float* pi0 = P + 512  + (1-tp)*128;    // SI[1-t']
        const float* pr1 = P + 768  + tp*128;        // TR[t']
        const float* pi1 = P + 1024 + (1-tp)*128;    // TI[1-t']
        for (int kk = 0; kk < 128; kk++){
          s += pr0[kk]*wr[kk*256] + sgn*pi0[kk]*wi[kk*256]
             + pr1[kk]*wr[32768 + kk*256] + sgn*pi1[kk]*wi[32768 + kk*256];
        }
      } else {
        int om = o - 896; int tp = om >> 7; c = om & 127;
        ch = tp ? 4 : 8;
        float sgn = tp ? 1.f : -1.f;
        const float* wr = m2w2r + c;                 // (2,128,128)
        const float* wi = m2w2i + c;
        const float* pr0 = P + 1280 + tp*128;
        const float* pi0 = P + 1536 + (1-tp)*128;
        const float* pr1 = P + 1792 + tp*128;
        const float* pi1 = P + 2048 + (1-tp)*128;
        for (int kk = 0; kk < 128; kk++){
          s += pr0[kk]*wr[kk*128] + sgn*pi0[kk]*wi[kk*128]
             + pr1[kk]*wr[16384 + kk*128] + sgn*pi1[kk]*wi[16384 + kk*128];
        }
      }
      Yb[ch*128 + c] = s;
    }
    __syncthreads();

    // ---- A7: grid (to_grid -> silu -> from_grid), split 324 pts over 2 halves ----
    {
      int half = tid >> 7, c = tid & 127;
      float z[9];
      #pragma unroll
      for (int i = 0; i < 9; i++) z[i] = 0.f;
      int p0 = half*162, p1 = p0 + 162;
      for (int p = p0; p < p1; p++){
        float gp = 0.f;
        #pragma unroll
        for (int i = 0; i < 9; i++) gp += tg[p*9 + i] * Yb[i*128 + c];
        float s = silu_f(gp);
        #pragma unroll
        for (int i = 0; i < 9; i++) z[i] += fg[p*9 + i] * s;
      }
      #pragma unroll
      for (int i = 0; i < 9; i++) Zb[half*1152 + i*128 + c] = z[i];
    }
    __syncthreads();

    // ---- A8: final wigner-transpose, accumulate ----
    for (int idx = tid; idx < 1152; idx += 256){
      int i2 = idx >> 7, c = idx & 127;
      float s = 0.f;
      for (int j = 0; j < 9; j++)
        s += wl[j*9 + i2] * (Zb[j*128 + c] + Zb[1152 + j*128 + c]);
      acc[idx] += s;
    }
  }

  __syncthreads();

  // ---- w_out projection: out[n,i2,:] = acc[i2,:] @ w_out[DEG[i2]] (+ b_out at i2==0) ----
  {
    int o = tid;  // 0..255
    for (int i2 = 0; i2 < 9; i2++){
      int deg = d_DEG[i2];
      const float* wp = w_out + (size_t)deg*32768 + o;   // (3,128,256)
      float s = (i2==0) ? b_out[o] : 0.f;
      for (int c = 0; c < 128; c++) s += acc[i2*128 + c] * wp[c*256];
      out[((size_t)n*9 + i2)*256 + o] = s;
    }
  }
}

// ---------------- host ----------------
extern "C" void kernel_launch(void* const* d_in, const int* in_sizes, int n_in,
                              void* d_out, int out_size, void* d_ws, size_t ws_size,
                              hipStream_t stream){
  const float* x     = (const float*)d_in[0];
  const float* attn  = (const float*)d_in[1];
  const float* wig   = (const float*)d_in[2];
  const float* tg    = (const float*)d_in[3];
  const float* fg    = (const float*)d_in[4];
  const float* w_in  = (const float*)d_in[5];
  const float* b_in  = (const float*)d_in[6];
  const float* w_out = (const float*)d_in[7];
  const float* b_out = (const float*)d_in[8];
  const float* es    = (const float*)d_in[9];
  const float* et    = (const float*)d_in[10];
  const float* fdw   = (const float*)d_in[11];
  const float* fdb   = (const float*)d_in[12];
  const float* few   = (const float*)d_in[13];
  const float* feb   = (const float*)d_in[14];
  const float* d0w   = (const float*)d_in[15];
  const float* d0b   = (const float*)d_in[16];
  const float* m0w1  = (const float*)d_in[17];
  const float* m0w2  = (const float*)d_in[18];
  const float* m1dw  = (const float*)d_in[19];
  const float* m1db  = (const float*)d_in[20];
  const float* m1w1r = (const float*)d_in[21];
  const float* m1w2r = (const float*)d_in[22];
  const float* m1w1i = (const float*)d_in[23];
  const float* m1w2i = (const float*)d_in[24];
  const float* m2dw  = (const float*)d_in[25];
  const float* m2db  = (const float*)d_in[26];
  const float* m2w1r = (const float*)d_in[27];
  const float* m2w2r = (const float*)d_in[28];
  const float* m2w1i = (const float*)d_in[29];
  const float* m2w2i = (const float*)d_in[30];
  const int*   an    = (const int*)d_in[31];
  const int*   esrc  = (const int*)d_in[32];
  const void*  maskp = d_in[33];

  int* FLAG = (int*)d_ws;

  k_detect<<<1,256,0,stream>>>((const unsigned int*)maskp, FLAG);
  k_mega<<<512,256,0,stream>>>(
      x, w_in, b_in, attn, fdw, fdb, few, feb, es, et, an, esrc,
      d0w, d0b, m1dw, m1db, m2dw, m2db,
      m0w1, m0w2, m1w1r, m1w2r, m1w1i, m1w2i, m2w1r, m2w2r, m2w1i, m2w2i,
      wig, tg, fg, w_out, b_out, maskp, FLAG, (float*)d_out);
}